// Round 6
// baseline (522.587 us; speedup 1.0000x reference)
//
#include <hip/hip_runtime.h>
#include <hip/hip_bf16.h>

#define N_NODES  50000
#define N_EDGES  800000
#define ND       64
#define ED       32
#define MSGD     128
#define HIDD     256
#define N_AGENTS 25000
#define EPAD     800064   // N_EDGES + 64 (tile padding)

typedef _Float16 f16;
typedef __attribute__((ext_vector_type(4))) _Float16 f16x4;
typedef __attribute__((ext_vector_type(8))) _Float16 f16x8;
typedef __attribute__((ext_vector_type(4))) float f32x4;
typedef unsigned short u16;
typedef unsigned int   u32;
typedef unsigned long long u64;

// ============================================================================
// compact + nf->f16 + weight pack fused.
// Blocks [0, 3125): compact path. Blocks [3125, 3209): pack path.
// ============================================================================
__global__ __launch_bounds__(256) void compact_pack_kernel(
    const int* __restrict__ recv, const float* __restrict__ nf,
    f16* __restrict__ nf16, int* __restrict__ rankb, int* __restrict__ deg,
    const float* __restrict__ W1, const float* __restrict__ W2,
    const float* __restrict__ Wh1, const float* __restrict__ Wh2,
    f16* __restrict__ F1, f16* __restrict__ F2,
    f16* __restrict__ F3, f16* __restrict__ F4)
{
    int b = blockIdx.x;
    if (b >= N_EDGES / 256) {
        // frag for 16x16x32: lane l, elem j <-> W[k=ks*32+(l>>4)*8+j][n=nt*16+(l&15)]
        int tid  = (b - N_EDGES / 256) * 256 + threadIdx.x;
        int grp  = tid >> 6, lane = tid & 63;
        const float* W; f16* D; int NT, stride, gl;
        if      (grp < 80)  { W = W1;  D = F1; NT = 16; stride = 256; gl = grp; }
        else if (grp < 144) { W = W2;  D = F2; NT = 8;  stride = 128; gl = grp - 80; }
        else if (grp < 208) { W = Wh1; D = F3; NT = 16; stride = 256; gl = grp - 144; }
        else if (grp < 336) { W = Wh2; D = F4; NT = 16; stride = 256; gl = grp - 208; }
        else return;
        int ks = gl / NT, nt = gl - ks * NT;
        int n  = nt * 16 + (lane & 15);
        int k0 = ks * 32 + (lane >> 4) * 8;
        f16* dst = D + ((size_t)gl * 64 + lane) * 8;
        #pragma unroll
        for (int j = 0; j < 8; ++j)
            dst[j] = (f16)W[(size_t)(k0 + j) * stride + n];
        return;
    }
    int i = b * 256 + threadIdx.x;
    {   // nf -> f16 (coalesced float4 read, f16x4 write)
        float4 v = ((const float4*)nf)[i];
        f16x4 h;
        h.x = (f16)v.x; h.y = (f16)v.y; h.z = (f16)v.z; h.w = (f16)v.w;
        ((f16x4*)nf16)[i] = h;
    }
    int r = recv[i];
    if (r < N_AGENTS)
        rankb[i] = atomicAdd(&deg[r], 1);   // 25k addresses, pipelined (R14)
}

// ============================================================================
// prefix: exclusive scan deg -> off[25001] (single block)
// ============================================================================
__global__ __launch_bounds__(1024) void prefix_kernel(
    const int* __restrict__ deg, int* __restrict__ off)
{
    __shared__ int part[1024];
    int t = threadIdx.x;
    int i0 = t * 25;
    int s = 0;
    #pragma unroll 1
    for (int i = 0; i < 25; ++i) {
        int idx = i0 + i;
        if (idx < N_AGENTS) s += deg[idx];
    }
    part[t] = s;
    __syncthreads();
    for (int d = 1; d < 1024; d <<= 1) {
        int v = (t >= d) ? part[t - d] : 0;
        __syncthreads();
        part[t] += v;
        __syncthreads();
    }
    int run = (t == 0) ? 0 : part[t - 1];
    #pragma unroll 1
    for (int i = 0; i < 25; ++i) {
        int idx = i0 + i;
        if (idx < N_AGENTS) {
            off[idx] = run;
            run += deg[idx];
        }
    }
    if (t == 1023) off[N_AGENTS] = part[1023];
}

// ============================================================================
// scatter (no atomics): iterate ALL edges; pos = off[recv] + rankb.
// ============================================================================
__global__ __launch_bounds__(256) void scatter_kernel(
    const int* __restrict__ recv, const int* __restrict__ send,
    const int* __restrict__ rankb, const int* __restrict__ off,
    int* __restrict__ eidb, int* __restrict__ sendb, int* __restrict__ recvb)
{
    int i = blockIdx.x * 256 + threadIdx.x;
    int r = recv[i];
    if (r < N_AGENTS) {
        int pos = off[r] + rankb[i];
        eidb[pos]  = i;
        sendb[pos] = send[i];
        recvb[pos] = r;
    }
}

// ============================================================================
// Edge MLP + FUSED partial aggregation (R17).
// Staging + MFMA phases byte-identical to R14 (147 us, FETCH 71 MB verified).
// HARD RULE (R8/R9/R15): staging = combined load+ds_write ROLLED loop +
// __syncthreads. Grid 512 (R12/R16: 768 and 1024 both regress).
// R17 change is ONLY the post-B2 tail: instead of writing msg (197 MB) +
// evals to HBM for agg_agent to re-read, finish the softmax-weighted sums
// here: tiles are CSR-sorted by receiver (~2-4 receivers/tile), so
//   den[r]  += sum of e = exp(logit) over the tile's rows of r  (wave-seg reduce)
//   aggr[r][c] += sum of e*msg[row][c] over runs               (seg col reduce)
// via fire-and-forget f32 atomics (~770/tile spread over 3.2M addresses).
// Kills 400 MB of round-trip traffic + the 197 MB msg buffer (cold pages).
// ============================================================================
__global__ __launch_bounds__(512, 4) void edge_mlp_mfma(
    const f16* __restrict__ nf16, const float* __restrict__ ef,
    const f16* __restrict__ F1, const f16* __restrict__ F2,
    const float* __restrict__ b1, const float* __restrict__ b2,
    const float* __restrict__ wg, const float* __restrict__ bg,
    const int* __restrict__ sendb, const int* __restrict__ recvb,
    const int* __restrict__ eidb, const int* __restrict__ cnt,
    float* __restrict__ aggr, float* __restrict__ den)
{
    __shared__ __align__(16) f16 XF[2][10][64][8];  // 20 KB (double buffer)
    __shared__ __align__(16) f16 HB[16][64][8];     // 16 KB
    __shared__ __align__(16) f16 msgt[32][136];     // 8.5 KB
    __shared__ float lpart[8][64];                  // 2 KB (cols 32-63 zeroed)
    __shared__ float evt[64];
    __shared__ int   recvt[64];

    const int tid  = threadIdx.x;
    const int wv   = tid >> 6;
    const int lane = tid & 63;
    const int q    = lane >> 4;
    const int li   = lane & 15;
    const int cntv   = cnt[0];
    const int ntiles = (cntv + 31) >> 5;

    // XCD-chunked tile assignment:
    const int xcd   = blockIdx.x & 7;
    const int bslot = blockIdx.x >> 3;
    const int tstep = gridDim.x >> 3;          // blocks per XCD
    const int T8    = (ntiles + 7) >> 3;
    const int tend  = min((xcd + 1) * T8, ntiles);
    const int t0    = xcd * T8 + bslot;

    // zero the never-written lpart columns read by the gate phase
    if (tid < 256) lpart[tid >> 5][32 + (tid & 31)] = 0.f;

    // stationary weight fragments: W1 2 col-tiles + W2 1 col-tile per wave
    f16x8 w1[2][5], w2[8];
    #pragma unroll
    for (int ntl = 0; ntl < 2; ++ntl)
        #pragma unroll
        for (int ks = 0; ks < 5; ++ks)
            w1[ntl][ks] = *(const f16x8*)(F1 + (((size_t)(ks * 16 + 2 * wv + ntl)) * 64 + lane) * 8);
    #pragma unroll
    for (int ks = 0; ks < 8; ++ks)
        w2[ks] = *(const f16x8*)(F2 + (((size_t)(ks * 8 + wv)) * 64 + lane) * 8);

    const float4 ba  = *(const float4*)&b1[wv * 32 + q * 4];
    const float4 bb  = *(const float4*)&b1[wv * 32 + 16 + q * 4];
    const float4 bc  = *(const float4*)&b2[wv * 16 + q * 4];
    const float4 wg4 = *(const float4*)&wg[wv * 16 + q * 4];
    const float  bgv = bg[0];

    // ---- prologue: stage first tile into XF[0] (R10 idiom — rolled) ----
    if (t0 < tend) {
        const int e0p = t0 * 32;
        f16 (*XFd)[64][8] = XF[0];
        for (int idx = tid; idx < 768; idx += 512) {
            int e = idx / 24, g = idx - e * 24;
            int cp = e0p + e;
            if (g < 16) {
                int node = (g < 8) ? sendb[cp] : recvb[cp];
                f16x8 h = *(const f16x8*)(nf16 + (size_t)node * 64 + (g & 7) * 8);
                int slt = (e >> 4) * 5 + (g >> 2);
                int ln  = (e & 15) + 16 * (g & 3);
                *(f16x8*)&XFd[slt][ln][0] = h;
            } else {
                int eid = eidb[cp];
                float4 v = ((const float4*)ef)[(size_t)eid * 8 + (g - 16)];
                int k0  = 128 + (g - 16) * 4;
                int slt = (e >> 4) * 5 + 4;
                int ln  = (e & 15) + 16 * ((k0 & 31) >> 3);
                int j0  = k0 & 7;
                f16x4 h;
                h.x = (f16)v.x; h.y = (f16)v.y; h.z = (f16)v.z; h.w = (f16)v.w;
                *(f16x4*)&XFd[slt][ln][j0] = h;
            }
        }
    }
    __syncthreads();

    int p = 0;
    for (int t = t0; t < tend; t += tstep) {
        const int e0 = t * 32;
        const int tn = t + tstep;

        // ---- stage NEXT tile into XF[p^1] — no barrier before layer1 ----
        if (tn < tend) {
            const int e0n = tn * 32;
            f16 (*XFd)[64][8] = XF[p ^ 1];
            for (int idx = tid; idx < 768; idx += 512) {
                int e = idx / 24, g = idx - e * 24;
                int cp = e0n + e;
                if (g < 16) {
                    int node = (g < 8) ? sendb[cp] : recvb[cp];
                    f16x8 h = *(const f16x8*)(nf16 + (size_t)node * 64 + (g & 7) * 8);
                    int slt = (e >> 4) * 5 + (g >> 2);
                    int ln  = (e & 15) + 16 * (g & 3);
                    *(f16x8*)&XFd[slt][ln][0] = h;
                } else {
                    int eid = eidb[cp];
                    float4 v = ((const float4*)ef)[(size_t)eid * 8 + (g - 16)];
                    int k0  = 128 + (g - 16) * 4;
                    int slt = (e >> 4) * 5 + 4;
                    int ln  = (e & 15) + 16 * ((k0 & 31) >> 3);
                    int j0  = k0 & 7;
                    f16x4 h;
                    h.x = (f16)v.x; h.y = (f16)v.y; h.z = (f16)v.z; h.w = (f16)v.w;
                    *(f16x4*)&XFd[slt][ln][j0] = h;
                }
            }
        }

        // ---- layer 1: h[col][edge] = W1^T x^T (from XF[p]) ----
        f32x4 acc[2][2];   // [eh][ntl]
        acc[0][0] = f32x4{ba.x, ba.y, ba.z, ba.w}; acc[1][0] = acc[0][0];
        acc[0][1] = f32x4{bb.x, bb.y, bb.z, bb.w}; acc[1][1] = acc[0][1];
        #pragma unroll
        for (int ks = 0; ks < 5; ++ks)
            #pragma unroll
            for (int eh = 0; eh < 2; ++eh) {
                f16x8 xh = *(const f16x8*)XF[p][eh * 5 + ks][lane];
                acc[eh][0] = __builtin_amdgcn_mfma_f32_16x16x32_f16(w1[0][ks], xh, acc[eh][0], 0, 0, 0);
                acc[eh][1] = __builtin_amdgcn_mfma_f32_16x16x32_f16(w1[1][ks], xh, acc[eh][1], 0, 0, 0);
            }
        // relu + stash h as layer-2 B frags
        #pragma unroll
        for (int eh = 0; eh < 2; ++eh)
            #pragma unroll
            for (int ntl = 0; ntl < 2; ++ntl) {
                f16x4 hv;
                hv.x = (f16)fmaxf(acc[eh][ntl][0], 0.f);
                hv.y = (f16)fmaxf(acc[eh][ntl][1], 0.f);
                hv.z = (f16)fmaxf(acc[eh][ntl][2], 0.f);
                hv.w = (f16)fmaxf(acc[eh][ntl][3], 0.f);
                int l2 = li + 16 * (2 * ntl + (q >> 1));
                int j0 = (q & 1) * 4;
                *(f16x4*)&HB[eh * 8 + wv][l2][j0] = hv;
            }
        __syncthreads();   // B1: HB ready; XF[p^1] staged

        // ---- layer 2: msg[col][edge] = W2^T h^T ----
        f32x4 acc2[2];
        acc2[0] = f32x4{bc.x, bc.y, bc.z, bc.w}; acc2[1] = acc2[0];
        #pragma unroll
        for (int ks2 = 0; ks2 < 8; ++ks2)
            #pragma unroll
            for (int eh = 0; eh < 2; ++eh) {
                f16x8 hh = *(const f16x8*)HB[eh * 8 + ks2][lane];
                acc2[eh] = __builtin_amdgcn_mfma_f32_16x16x32_f16(w2[ks2], hh, acc2[eh], 0, 0, 0);
            }
        // relu + gate partial + msg stash
        {
            float pr[2];
            #pragma unroll
            for (int eh = 0; eh < 2; ++eh) {
                float v0 = fmaxf(acc2[eh][0], 0.f);
                float v1 = fmaxf(acc2[eh][1], 0.f);
                float v2 = fmaxf(acc2[eh][2], 0.f);
                float v3 = fmaxf(acc2[eh][3], 0.f);
                f16x4 mm;
                mm.x = (f16)v0; mm.y = (f16)v1; mm.z = (f16)v2; mm.w = (f16)v3;
                *(f16x4*)&msgt[eh * 16 + li][wv * 16 + q * 4] = mm;
                float pp = v0 * wg4.x + v1 * wg4.y + v2 * wg4.z + v3 * wg4.w;
                pp += __shfl_xor(pp, 16, 64);
                pp += __shfl_xor(pp, 32, 64);
                pr[eh] = pp;
            }
            if (lane < 16) {
                lpart[wv][li]      = pr[0];
                lpart[wv][16 + li] = pr[1];
            }
        }
        __syncthreads();   // B2: msgt/lpart ready

        // ---- gate e = exp(logit); den atomics via wave-segmented reduce ----
        if (tid < 64) {
            int r = -1;
            int pos = e0 + tid;
            if (tid < 32 && pos < cntv) r = recvt[0] = 0, r = recvb[pos]; // (load)
            float s2 = bgv;
            #pragma unroll
            for (int w = 0; w < 8; ++w) s2 += lpart[w][tid];
            float e = expf(s2);
            if (r < 0) e = 0.f;
            evt[tid]   = e;
            recvt[tid] = r;
            // segmented suffix-sum over contiguous equal-r runs (runs <= 32)
            float a = e;
            #pragma unroll
            for (int k = 1; k <= 16; k <<= 1) {
                int   rn = __shfl_down(r, k, 64);
                float an = __shfl_down(a, k, 64);
                if (tid + k < 64 && rn == r) a += an;
            }
            int rp = __shfl_up(r, 1, 64);
            if ((tid == 0 || r != rp) && r >= 0)
                atomicAdd(&den[r], a);
        }
        __syncthreads();   // B2b: evt/recvt ready

        // ---- segmented column reduce + atomic aggr (all 512 threads) ----
        {
            int col = tid >> 2, seg = tid & 3;
            float run = 0.f; int rprev = -1;
            #pragma unroll
            for (int j = 0; j < 8; ++j) {
                int row = seg * 8 + j;
                int r = recvt[row];
                if (r != rprev) {
                    if (rprev >= 0)
                        atomicAdd(&aggr[(size_t)rprev * 128 + col], run);
                    run = 0.f; rprev = r;
                }
                run += evt[row] * (float)msgt[row][col];
            }
            if (rprev >= 0)
                atomicAdd(&aggr[(size_t)rprev * 128 + col], run);
        }
        p ^= 1;
    }
}

// ============================================================================
// Agent MLP. Aggregation is already done (aggr/den from edge_mlp atomics):
// just normalize into XA fragments and run the 2-layer fp16-MFMA MLP.
// ============================================================================
__global__ __launch_bounds__(1024, 4) void agg_agent_mfma(
    const float* __restrict__ aggr, const float* __restrict__ den,
    const f16* __restrict__ F3, const f16* __restrict__ F4,
    const float* __restrict__ bh1, const float* __restrict__ bh2,
    const float* __restrict__ Wout, const float* __restrict__ bout,
    float* __restrict__ out)
{
    __shared__ __align__(16) f16 XA[8][64][8];     // 8 KB
    __shared__ __align__(16) f16 HB2[16][64][8];   // 16 KB
    __shared__ float lpart[16][32];

    const int tid  = threadIdx.x;
    const int wv   = tid >> 6;
    const int lane = tid & 63;
    const int q    = lane >> 4;
    const int li   = lane & 15;
    const int a0i  = blockIdx.x * 32;

    // ---- normalize aggr into XA fragment layout ----
    {
        int g = tid >> 5, c = tid & 31;   // receiver a0i+g, cols [c*4, c*4+4)
        int r = a0i + g;
        float4 a = make_float4(0.f, 0.f, 0.f, 0.f);
        float d = 1e-9f;
        if (r < N_AGENTS) {
            a = *(const float4*)&aggr[(size_t)r * 128 + c * 4];
            d += den[r];
        }
        float inv = 1.0f / d;
        int k0   = c * 4;
        int slot = (g >> 4) * 4 + (k0 >> 5);
        int ln   = (g & 15) + 16 * ((k0 & 31) >> 3);
        int j0   = k0 & 7;
        f16x4 h;
        h.x = (f16)(a.x * inv); h.y = (f16)(a.y * inv);
        h.z = (f16)(a.z * inv); h.w = (f16)(a.w * inv);
        *(f16x4*)&XA[slot][ln][j0] = h;
    }
    __syncthreads();

    // ---- weight fragments + layer 1 ----
    f16x8 wh1[4], wh2[8];
    #pragma unroll
    for (int ks = 0; ks < 4; ++ks)
        wh1[ks] = *(const f16x8*)(F3 + (((size_t)(ks * 16 + wv)) * 64 + lane) * 8);
    #pragma unroll
    for (int ks = 0; ks < 8; ++ks)
        wh2[ks] = *(const f16x8*)(F4 + (((size_t)(ks * 16 + wv)) * 64 + lane) * 8);

    f32x4 acc[2] = {};
    #pragma unroll
    for (int ks = 0; ks < 4; ++ks)
        #pragma unroll
        for (int eh = 0; eh < 2; ++eh) {
            f16x8 xh = *(const f16x8*)XA[eh * 4 + ks][lane];
            acc[eh] = __builtin_amdgcn_mfma_f32_16x16x32_f16(wh1[ks], xh, acc[eh], 0, 0, 0);
        }
    {
        const float4 b1v = ((const float4*)bh1)[wv * 4 + q];
        #pragma unroll
        for (int eh = 0; eh < 2; ++eh) {
            f16x4 hv;
            hv.x = (f16)fmaxf(acc[eh][0] + b1v.x, 0.f);
            hv.y = (f16)fmaxf(acc[eh][1] + b1v.y, 0.f);
            hv.z = (f16)fmaxf(acc[eh][2] + b1v.z, 0.f);
            hv.w = (f16)fmaxf(acc[eh][3] + b1v.w, 0.f);
            int l2 = li + 16 * ((wv & 1) * 2 + (q >> 1));
            int j0 = (q & 1) * 4;
            *(f16x4*)&HB2[eh * 8 + (wv >> 1)][l2][j0] = hv;
        }
    }
    __syncthreads();

    // ---- layer 2 + output partial ----
    f32x4 acc2[2] = {};
    #pragma unroll
    for (int ks2 = 0; ks2 < 8; ++ks2)
        #pragma unroll
        for (int eh = 0; eh < 2; ++eh) {
            f16x8 hh = *(const f16x8*)HB2[eh * 8 + ks2][lane];
            acc2[eh] = __builtin_amdgcn_mfma_f32_16x16x32_f16(wh2[ks2], hh, acc2[eh], 0, 0, 0);
        }
    {
        const float4 b2v = ((const float4*)bh2)[wv * 4 + q];
        const float4 wo4 = ((const float4*)Wout)[wv * 4 + q];
        float pr[2];
        #pragma unroll
        for (int eh = 0; eh < 2; ++eh) {
            float pp = fmaxf(acc2[eh][0] + b2v.x, 0.f) * wo4.x
                     + fmaxf(acc2[eh][1] + b2v.y, 0.f) * wo4.y
                     + fmaxf(acc2[eh][2] + b2v.z, 0.f) * wo4.z
                     + fmaxf(acc2[eh][3] + b2v.w, 0.f) * wo4.w;
            pp += __shfl_xor(pp, 16, 64);
            pp += __shfl_xor(pp, 32, 64);
            pr[eh] = pp;
        }
        if (lane < 16) {
            lpart[wv][li]      = pr[0];
            lpart[wv][16 + li] = pr[1];
        }
    }
    __syncthreads();

    if (tid < 32 && a0i + tid < N_AGENTS) {
        float s = bout[0];
        #pragma unroll
        for (int w = 0; w < 16; ++w) s += lpart[w][tid];
        out[a0i + tid] = tanhf(s);
    }
}

// ============================================================================
extern "C" void kernel_launch(void* const* d_in, const int* in_sizes, int n_in,
                              void* d_out, int out_size, void* d_ws, size_t ws_size,
                              hipStream_t stream)
{
    const float* nf   = (const float*)d_in[0];
    const float* ef   = (const float*)d_in[1];
    const float* W1   = (const float*)d_in[2];
    const float* b1   = (const float*)d_in[3];
    const float* W2   = (const float*)d_in[4];
    const float* b2   = (const float*)d_in[5];
    const float* wg   = (const float*)d_in[6];
    const float* bg   = (const float*)d_in[7];
    const float* Wh1  = (const float*)d_in[8];
    const float* bh1  = (const float*)d_in[9];
    const float* Wh2  = (const float*)d_in[10];
    const float* bh2  = (const float*)d_in[11];
    const float* Wout = (const float*)d_in[12];
    const float* bout = (const float*)d_in[13];
    const int*   send = (const int*)d_in[14];
    const int*   recv = (const int*)d_in[15];

    // workspace: [deg|eidb|sendb|recvb|den|aggr] zeroed (tail slots must
    // gather row 0; den/aggr are atomic accumulators), then the rest
    char* ws = (char*)d_ws;
    int* deg    = (int*)ws;            ws += (size_t)N_AGENTS * 4;
    int* eidb   = (int*)ws;            ws += (size_t)EPAD * 4;
    int* sendb  = (int*)ws;            ws += (size_t)EPAD * 4;
    int* recvb  = (int*)ws;            ws += (size_t)EPAD * 4;
    float* den  = (float*)ws;          ws += (size_t)N_AGENTS * 4;
    float* aggr = (float*)ws;          ws += (size_t)N_AGENTS * 128 * 4;
    size_t zero_bytes = (size_t)(ws - (char*)d_ws);
    int* rankb  = (int*)ws;            ws += (size_t)N_EDGES * 4;
    int* off    = (int*)ws;            ws += (size_t)(N_AGENTS + 8) * 4;
    f16* nf16   = (f16*)ws;            ws += (size_t)N_NODES * ND * 2;
    f16* F1     = (f16*)ws;            ws += (size_t)160 * 256 * 2;
    f16* F2     = (f16*)ws;            ws += (size_t)256 * 128 * 2;
    f16* F3     = (f16*)ws;            ws += (size_t)128 * 256 * 2;
    f16* F4     = (f16*)ws;            ws += (size_t)256 * 256 * 2;

    hipMemsetAsync(d_ws, 0, zero_bytes, stream);

    compact_pack_kernel<<<N_EDGES / 256 + 84, 256, 0, stream>>>(
        recv, nf, nf16, rankb, deg, W1, W2, Wh1, Wh2, F1, F2, F3, F4);
    prefix_kernel<<<1, 1024, 0, stream>>>(deg, off);
    scatter_kernel<<<N_EDGES / 256, 256, 0, stream>>>(
        recv, send, rankb, off, eidb, sendb, recvb);
    edge_mlp_mfma<<<512, 512, 0, stream>>>(
        nf16, ef, F1, F2, b1, b2, wg, bg, sendb, recvb, eidb, off + N_AGENTS,
        aggr, den);
    agg_agent_mfma<<<(N_AGENTS + 31) / 32, 1024, 0, stream>>>(
        aggr, den, F3, F4, bh1, bh2, Wout, bout, (float*)d_out);
}

// Round 8
// 519.189 us; speedup vs baseline: 1.0065x; 1.0065x over previous
//
#include <hip/hip_runtime.h>
#include <hip/hip_bf16.h>

#define N_NODES  50000
#define N_EDGES  800000
#define ND       64
#define ED       32
#define MSGD     128
#define HIDD     256
#define N_AGENTS 25000
#define EPAD     800064   // N_EDGES + 64 (tile padding)
#define RPB      49       // receivers per edge-MLP block (511 blocks)

typedef _Float16 f16;
typedef __attribute__((ext_vector_type(4))) _Float16 f16x4;
typedef __attribute__((ext_vector_type(8))) _Float16 f16x8;
typedef __attribute__((ext_vector_type(4))) float f32x4;
typedef unsigned short u16;
typedef unsigned int   u32;
typedef unsigned long long u64;

// ============================================================================
// compact + nf->f16 + weight pack fused.
// Blocks [0, 3125): compact path. Blocks [3125, 3209): pack path.
// ============================================================================
__global__ __launch_bounds__(256) void compact_pack_kernel(
    const int* __restrict__ recv, const float* __restrict__ nf,
    f16* __restrict__ nf16, int* __restrict__ rankb, int* __restrict__ deg,
    const float* __restrict__ W1, const float* __restrict__ W2,
    const float* __restrict__ Wh1, const float* __restrict__ Wh2,
    f16* __restrict__ F1, f16* __restrict__ F2,
    f16* __restrict__ F3, f16* __restrict__ F4)
{
    int b = blockIdx.x;
    if (b >= N_EDGES / 256) {
        // frag for 16x16x32: lane l, elem j <-> W[k=ks*32+(l>>4)*8+j][n=nt*16+(l&15)]
        int tid  = (b - N_EDGES / 256) * 256 + threadIdx.x;
        int grp  = tid >> 6, lane = tid & 63;
        const float* W; f16* D; int NT, stride, gl;
        if      (grp < 80)  { W = W1;  D = F1; NT = 16; stride = 256; gl = grp; }
        else if (grp < 144) { W = W2;  D = F2; NT = 8;  stride = 128; gl = grp - 80; }
        else if (grp < 208) { W = Wh1; D = F3; NT = 16; stride = 256; gl = grp - 144; }
        else if (grp < 336) { W = Wh2; D = F4; NT = 16; stride = 256; gl = grp - 208; }
        else return;
        int ks = gl / NT, nt = gl - ks * NT;
        int n  = nt * 16 + (lane & 15);
        int k0 = ks * 32 + (lane >> 4) * 8;
        f16* dst = D + ((size_t)gl * 64 + lane) * 8;
        #pragma unroll
        for (int j = 0; j < 8; ++j)
            dst[j] = (f16)W[(size_t)(k0 + j) * stride + n];
        return;
    }
    int i = b * 256 + threadIdx.x;
    {   // nf -> f16 (coalesced float4 read, f16x4 write)
        float4 v = ((const float4*)nf)[i];
        f16x4 h;
        h.x = (f16)v.x; h.y = (f16)v.y; h.z = (f16)v.z; h.w = (f16)v.w;
        ((f16x4*)nf16)[i] = h;
    }
    int r = recv[i];
    if (r < N_AGENTS)
        rankb[i] = atomicAdd(&deg[r], 1);   // 25k addresses, pipelined (R14)
}

// ============================================================================
// prefix: exclusive scan deg -> off[25001] (single block)
// ============================================================================
__global__ __launch_bounds__(1024) void prefix_kernel(
    const int* __restrict__ deg, int* __restrict__ off)
{
    __shared__ int part[1024];
    int t = threadIdx.x;
    int i0 = t * 25;
    int s = 0;
    #pragma unroll 1
    for (int i = 0; i < 25; ++i) {
        int idx = i0 + i;
        if (idx < N_AGENTS) s += deg[idx];
    }
    part[t] = s;
    __syncthreads();
    for (int d = 1; d < 1024; d <<= 1) {
        int v = (t >= d) ? part[t - d] : 0;
        __syncthreads();
        part[t] += v;
        __syncthreads();
    }
    int run = (t == 0) ? 0 : part[t - 1];
    #pragma unroll 1
    for (int i = 0; i < 25; ++i) {
        int idx = i0 + i;
        if (idx < N_AGENTS) {
            off[idx] = run;
            run += deg[idx];
        }
    }
    if (t == 1023) off[N_AGENTS] = part[1023];
}

// ============================================================================
// scatter (no atomics): iterate ALL edges; pos = off[recv] + rankb.
// ============================================================================
__global__ __launch_bounds__(256) void scatter_kernel(
    const int* __restrict__ recv, const int* __restrict__ send,
    const int* __restrict__ rankb, const int* __restrict__ off,
    int* __restrict__ eidb, int* __restrict__ sendb, int* __restrict__ recvb)
{
    int i = blockIdx.x * 256 + threadIdx.x;
    int r = recv[i];
    if (r < N_AGENTS) {
        int pos = off[r] + rankb[i];
        eidb[pos]  = i;
        sendb[pos] = send[i];
        recvb[pos] = r;
    }
}

// ============================================================================
// Edge MLP + owned aggregation (R18, resubmitted after infra timeout).
// R17 post-mortem: device-scope atomicAdd for aggr/den resolves at memory
// side on MI355X (per-XCD L2s non-coherent) -> 30M far RMWs, WRITE 136 MB,
// edge 277 us. R18: partition RECEIVERS across blocks (RPB=49, 511 blocks).
// Each block owns its receivers' contiguous CSR edge range -> aggregation is
// a per-thread register run-sum (128 col threads + 1 den thread), flushed
// with PLAIN coalesced stores on segment close (~1.5/tile, ZERO atomics,
// uniform branches). msg/evals HBM round trip (300 MB) eliminated.
// Staging + MFMA phases byte-identical to R14 (147 us, FETCH 71 MB verified);
// only the tile base changes (eb0 + t*32). HARD RULE (R8/R9/R15): staging =
// combined load+ds_write ROLLED loop + __syncthreads.
// ============================================================================
__global__ __launch_bounds__(512, 4) void edge_mlp_mfma(
    const f16* __restrict__ nf16, const float* __restrict__ ef,
    const f16* __restrict__ F1, const f16* __restrict__ F2,
    const float* __restrict__ b1, const float* __restrict__ b2,
    const float* __restrict__ wg, const float* __restrict__ bg,
    const int* __restrict__ sendb, const int* __restrict__ recvb,
    const int* __restrict__ eidb, const int* __restrict__ off,
    float* __restrict__ aggr, float* __restrict__ den)
{
    __shared__ __align__(16) f16 XF[2][10][64][8];  // 20 KB (double buffer)
    __shared__ __align__(16) f16 HB[16][64][8];     // 16 KB
    __shared__ __align__(16) f16 msgt[32][136];     // 8.5 KB
    __shared__ float lpart[8][32];
    __shared__ float evt[32];
    __shared__ int   recvt[32];

    const int tid  = threadIdx.x;
    const int wv   = tid >> 6;
    const int lane = tid & 63;
    const int q    = lane >> 4;
    const int li   = lane & 15;

    // ---- owned receiver range -> contiguous CSR edge range ----
    const int rb0 = blockIdx.x * RPB;
    if (rb0 >= N_AGENTS) return;
    const int rb1 = min(rb0 + RPB, N_AGENTS);
    const int eb0 = off[rb0];
    const int eb1 = off[rb1];
    const int ntiles = (eb1 - eb0 + 31) >> 5;

    // stationary weight fragments: W1 2 col-tiles + W2 1 col-tile per wave
    f16x8 w1[2][5], w2[8];
    #pragma unroll
    for (int ntl = 0; ntl < 2; ++ntl)
        #pragma unroll
        for (int ks = 0; ks < 5; ++ks)
            w1[ntl][ks] = *(const f16x8*)(F1 + (((size_t)(ks * 16 + 2 * wv + ntl)) * 64 + lane) * 8);
    #pragma unroll
    for (int ks = 0; ks < 8; ++ks)
        w2[ks] = *(const f16x8*)(F2 + (((size_t)(ks * 8 + wv)) * 64 + lane) * 8);

    const float4 ba  = *(const float4*)&b1[wv * 32 + q * 4];
    const float4 bb  = *(const float4*)&b1[wv * 32 + 16 + q * 4];
    const float4 bc  = *(const float4*)&b2[wv * 16 + q * 4];
    const float4 wg4 = *(const float4*)&wg[wv * 16 + q * 4];
    const float  bgv = bg[0];

    // persistent aggregation state (uniform ropen; per-thread accumulator)
    const int  col   = tid & 127;
    const bool isden = (tid == 128);
    const bool isagg = (tid < 128);
    float accv = 0.f, dacc = 0.f;
    int   ropen = -1;

    // ---- prologue: stage first tile into XF[0] (R10 idiom — rolled) ----
    if (ntiles > 0) {
        const int e0p = eb0;
        f16 (*XFd)[64][8] = XF[0];
        for (int idx = tid; idx < 768; idx += 512) {
            int e = idx / 24, g = idx - e * 24;
            int cp = e0p + e;
            if (g < 16) {
                int node = (g < 8) ? sendb[cp] : recvb[cp];
                f16x8 h = *(const f16x8*)(nf16 + (size_t)node * 64 + (g & 7) * 8);
                int slt = (e >> 4) * 5 + (g >> 2);
                int ln  = (e & 15) + 16 * (g & 3);
                *(f16x8*)&XFd[slt][ln][0] = h;
            } else {
                int eid = eidb[cp];
                float4 v = ((const float4*)ef)[(size_t)eid * 8 + (g - 16)];
                int k0  = 128 + (g - 16) * 4;
                int slt = (e >> 4) * 5 + 4;
                int ln  = (e & 15) + 16 * ((k0 & 31) >> 3);
                int j0  = k0 & 7;
                f16x4 h;
                h.x = (f16)v.x; h.y = (f16)v.y; h.z = (f16)v.z; h.w = (f16)v.w;
                *(f16x4*)&XFd[slt][ln][j0] = h;
            }
        }
    }
    __syncthreads();

    int p = 0;
    for (int t = 0; t < ntiles; ++t) {
        const int e0 = eb0 + t * 32;

        // ---- stage NEXT tile into XF[p^1] — no barrier before layer1 ----
        if (t + 1 < ntiles) {
            const int e0n = e0 + 32;
            f16 (*XFd)[64][8] = XF[p ^ 1];
            for (int idx = tid; idx < 768; idx += 512) {
                int e = idx / 24, g = idx - e * 24;
                int cp = e0n + e;
                if (g < 16) {
                    int node = (g < 8) ? sendb[cp] : recvb[cp];
                    f16x8 h = *(const f16x8*)(nf16 + (size_t)node * 64 + (g & 7) * 8);
                    int slt = (e >> 4) * 5 + (g >> 2);
                    int ln  = (e & 15) + 16 * (g & 3);
                    *(f16x8*)&XFd[slt][ln][0] = h;
                } else {
                    int eid = eidb[cp];
                    float4 v = ((const float4*)ef)[(size_t)eid * 8 + (g - 16)];
                    int k0  = 128 + (g - 16) * 4;
                    int slt = (e >> 4) * 5 + 4;
                    int ln  = (e & 15) + 16 * ((k0 & 31) >> 3);
                    int j0  = k0 & 7;
                    f16x4 h;
                    h.x = (f16)v.x; h.y = (f16)v.y; h.z = (f16)v.z; h.w = (f16)v.w;
                    *(f16x4*)&XFd[slt][ln][j0] = h;
                }
            }
        }

        // ---- layer 1: h[col][edge] = W1^T x^T (from XF[p]) ----
        f32x4 acc[2][2];   // [eh][ntl]
        acc[0][0] = f32x4{ba.x, ba.y, ba.z, ba.w}; acc[1][0] = acc[0][0];
        acc[0][1] = f32x4{bb.x, bb.y, bb.z, bb.w}; acc[1][1] = acc[0][1];
        #pragma unroll
        for (int ks = 0; ks < 5; ++ks)
            #pragma unroll
            for (int eh = 0; eh < 2; ++eh) {
                f16x8 xh = *(const f16x8*)XF[p][eh * 5 + ks][lane];
                acc[eh][0] = __builtin_amdgcn_mfma_f32_16x16x32_f16(w1[0][ks], xh, acc[eh][0], 0, 0, 0);
                acc[eh][1] = __builtin_amdgcn_mfma_f32_16x16x32_f16(w1[1][ks], xh, acc[eh][1], 0, 0, 0);
            }
        // relu + stash h as layer-2 B frags
        #pragma unroll
        for (int eh = 0; eh < 2; ++eh)
            #pragma unroll
            for (int ntl = 0; ntl < 2; ++ntl) {
                f16x4 hv;
                hv.x = (f16)fmaxf(acc[eh][ntl][0], 0.f);
                hv.y = (f16)fmaxf(acc[eh][ntl][1], 0.f);
                hv.z = (f16)fmaxf(acc[eh][ntl][2], 0.f);
                hv.w = (f16)fmaxf(acc[eh][ntl][3], 0.f);
                int l2 = li + 16 * (2 * ntl + (q >> 1));
                int j0 = (q & 1) * 4;
                *(f16x4*)&HB[eh * 8 + wv][l2][j0] = hv;
            }
        __syncthreads();   // B1: HB ready; XF[p^1] staged

        // ---- layer 2: msg[col][edge] = W2^T h^T ----
        f32x4 acc2[2];
        acc2[0] = f32x4{bc.x, bc.y, bc.z, bc.w}; acc2[1] = acc2[0];
        #pragma unroll
        for (int ks2 = 0; ks2 < 8; ++ks2)
            #pragma unroll
            for (int eh = 0; eh < 2; ++eh) {
                f16x8 hh = *(const f16x8*)HB[eh * 8 + ks2][lane];
                acc2[eh] = __builtin_amdgcn_mfma_f32_16x16x32_f16(w2[ks2], hh, acc2[eh], 0, 0, 0);
            }
        // relu + gate partial + msg stash
        {
            float pr[2];
            #pragma unroll
            for (int eh = 0; eh < 2; ++eh) {
                float v0 = fmaxf(acc2[eh][0], 0.f);
                float v1 = fmaxf(acc2[eh][1], 0.f);
                float v2 = fmaxf(acc2[eh][2], 0.f);
                float v3 = fmaxf(acc2[eh][3], 0.f);
                f16x4 mm;
                mm.x = (f16)v0; mm.y = (f16)v1; mm.z = (f16)v2; mm.w = (f16)v3;
                *(f16x4*)&msgt[eh * 16 + li][wv * 16 + q * 4] = mm;
                float pp = v0 * wg4.x + v1 * wg4.y + v2 * wg4.z + v3 * wg4.w;
                pp += __shfl_xor(pp, 16, 64);
                pp += __shfl_xor(pp, 32, 64);
                pr[eh] = pp;
            }
            if (lane < 16) {
                lpart[wv][li]      = pr[0];
                lpart[wv][16 + li] = pr[1];
            }
        }
        __syncthreads();   // B2: msgt/lpart ready

        // ---- gate: e = exp(logit); publish evt/recvt for this tile ----
        if (tid < 32) {
            int pos = e0 + tid;
            int r = -1; float e = 0.f;
            if (pos < eb1) {
                r = recvb[pos];
                float s2 = bgv;
                #pragma unroll
                for (int w = 0; w < 8; ++w) s2 += lpart[w][tid];
                e = expf(s2);   // softmax shift-invariant; |logit|~O(5)
            }
            evt[tid]   = e;
            recvt[tid] = r;
        }
        __syncthreads();   // B2b: evt/recvt ready

        // ---- owned segmented accumulate (uniform branches, no atomics) ----
        if (tid < 129) {
            #pragma unroll 1
            for (int j = 0; j < 32; ++j) {
                int r = recvt[j];
                if (r != ropen) {
                    if (ropen >= 0) {
                        if (isden) den[ropen] = dacc;
                        else       aggr[(size_t)ropen * 128 + col] = accv;
                    }
                    accv = 0.f; dacc = 0.f; ropen = r;
                }
                if (r >= 0) {
                    float e = evt[j];
                    if (isagg) accv = fmaf(e, (float)msgt[j][col], accv);
                    else       dacc += e;
                }
            }
        }
        p ^= 1;
    }

    // ---- final flush of the open receiver ----
    if (tid < 129 && ropen >= 0) {
        if (isden) den[ropen] = dacc;
        else       aggr[(size_t)ropen * 128 + col] = accv;
    }
}

// ============================================================================
// Agent MLP. Aggregation already done (aggr/den owned-stores from edge_mlp):
// normalize into XA fragments and run the 2-layer fp16-MFMA MLP.
// ============================================================================
__global__ __launch_bounds__(1024, 4) void agg_agent_mfma(
    const float* __restrict__ aggr, const float* __restrict__ den,
    const f16* __restrict__ F3, const f16* __restrict__ F4,
    const float* __restrict__ bh1, const float* __restrict__ bh2,
    const float* __restrict__ Wout, const float* __restrict__ bout,
    float* __restrict__ out)
{
    __shared__ __align__(16) f16 XA[8][64][8];     // 8 KB
    __shared__ __align__(16) f16 HB2[16][64][8];   // 16 KB
    __shared__ float lpart[16][32];

    const int tid  = threadIdx.x;
    const int wv   = tid >> 6;
    const int lane = tid & 63;
    const int q    = lane >> 4;
    const int li   = lane & 15;
    const int a0i  = blockIdx.x * 32;

    // ---- normalize aggr into XA fragment layout ----
    {
        int g = tid >> 5, c = tid & 31;   // receiver a0i+g, cols [c*4, c*4+4)
        int r = a0i + g;
        float4 a = make_float4(0.f, 0.f, 0.f, 0.f);
        float d = 1e-9f;
        if (r < N_AGENTS) {
            a = *(const float4*)&aggr[(size_t)r * 128 + c * 4];
            d += den[r];
        }
        float inv = 1.0f / d;
        int k0   = c * 4;
        int slot = (g >> 4) * 4 + (k0 >> 5);
        int ln   = (g & 15) + 16 * ((k0 & 31) >> 3);
        int j0   = k0 & 7;
        f16x4 h;
        h.x = (f16)(a.x * inv); h.y = (f16)(a.y * inv);
        h.z = (f16)(a.z * inv); h.w = (f16)(a.w * inv);
        *(f16x4*)&XA[slot][ln][j0] = h;
    }
    __syncthreads();

    // ---- weight fragments + layer 1 ----
    f16x8 wh1[4], wh2[8];
    #pragma unroll
    for (int ks = 0; ks < 4; ++ks)
        wh1[ks] = *(const f16x8*)(F3 + (((size_t)(ks * 16 + wv)) * 64 + lane) * 8);
    #pragma unroll
    for (int ks = 0; ks < 8; ++ks)
        wh2[ks] = *(const f16x8*)(F4 + (((size_t)(ks * 16 + wv)) * 64 + lane) * 8);

    f32x4 acc[2] = {};
    #pragma unroll
    for (int ks = 0; ks < 4; ++ks)
        #pragma unroll
        for (int eh = 0; eh < 2; ++eh) {
            f16x8 xh = *(const f16x8*)XA[eh * 4 + ks][lane];
            acc[eh] = __builtin_amdgcn_mfma_f32_16x16x32_f16(wh1[ks], xh, acc[eh], 0, 0, 0);
        }
    {
        const float4 b1v = ((const float4*)bh1)[wv * 4 + q];
        #pragma unroll
        for (int eh = 0; eh < 2; ++eh) {
            f16x4 hv;
            hv.x = (f16)fmaxf(acc[eh][0] + b1v.x, 0.f);
            hv.y = (f16)fmaxf(acc[eh][1] + b1v.y, 0.f);
            hv.z = (f16)fmaxf(acc[eh][2] + b1v.z, 0.f);
            hv.w = (f16)fmaxf(acc[eh][3] + b1v.w, 0.f);
            int l2 = li + 16 * ((wv & 1) * 2 + (q >> 1));
            int j0 = (q & 1) * 4;
            *(f16x4*)&HB2[eh * 8 + (wv >> 1)][l2][j0] = hv;
        }
    }
    __syncthreads();

    // ---- layer 2 + output partial ----
    f32x4 acc2[2] = {};
    #pragma unroll
    for (int ks2 = 0; ks2 < 8; ++ks2)
        #pragma unroll
        for (int eh = 0; eh < 2; ++eh) {
            f16x8 hh = *(const f16x8*)HB2[eh * 8 + ks2][lane];
            acc2[eh] = __builtin_amdgcn_mfma_f32_16x16x32_f16(wh2[ks2], hh, acc2[eh], 0, 0, 0);
        }
    {
        const float4 b2v = ((const float4*)bh2)[wv * 4 + q];
        const float4 wo4 = ((const float4*)Wout)[wv * 4 + q];
        float pr[2];
        #pragma unroll
        for (int eh = 0; eh < 2; ++eh) {
            float pp = fmaxf(acc2[eh][0] + b2v.x, 0.f) * wo4.x
                     + fmaxf(acc2[eh][1] + b2v.y, 0.f) * wo4.y
                     + fmaxf(acc2[eh][2] + b2v.z, 0.f) * wo4.z
                     + fmaxf(acc2[eh][3] + b2v.w, 0.f) * wo4.w;
            pp += __shfl_xor(pp, 16, 64);
            pp += __shfl_xor(pp, 32, 64);
            pr[eh] = pp;
        }
        if (lane < 16) {
            lpart[wv][li]      = pr[0];
            lpart[wv][16 + li] = pr[1];
        }
    }
    __syncthreads();

    if (tid < 32 && a0i + tid < N_AGENTS) {
        float s = bout[0];
        #pragma unroll
        for (int w = 0; w < 16; ++w) s += lpart[w][tid];
        out[a0i + tid] = tanhf(s);
    }
}

// ============================================================================
extern "C" void kernel_launch(void* const* d_in, const int* in_sizes, int n_in,
                              void* d_out, int out_size, void* d_ws, size_t ws_size,
                              hipStream_t stream)
{
    const float* nf   = (const float*)d_in[0];
    const float* ef   = (const float*)d_in[1];
    const float* W1   = (const float*)d_in[2];
    const float* b1   = (const float*)d_in[3];
    const float* W2   = (const float*)d_in[4];
    const float* b2   = (const float*)d_in[5];
    const float* wg   = (const float*)d_in[6];
    const float* bg   = (const float*)d_in[7];
    const float* Wh1  = (const float*)d_in[8];
    const float* bh1  = (const float*)d_in[9];
    const float* Wh2  = (const float*)d_in[10];
    const float* bh2  = (const float*)d_in[11];
    const float* Wout = (const float*)d_in[12];
    const float* bout = (const float*)d_in[13];
    const int*   send = (const int*)d_in[14];
    const int*   recv = (const int*)d_in[15];

    // workspace: [deg|eidb|sendb|recvb|den|aggr] zeroed (tail slots must
    // gather row 0; deg-0 receivers need zero aggr/den), then the rest
    char* ws = (char*)d_ws;
    int* deg    = (int*)ws;            ws += (size_t)N_AGENTS * 4;
    int* eidb   = (int*)ws;            ws += (size_t)EPAD * 4;
    int* sendb  = (int*)ws;            ws += (size_t)EPAD * 4;
    int* recvb  = (int*)ws;            ws += (size_t)EPAD * 4;
    float* den  = (float*)ws;          ws += (size_t)N_AGENTS * 4;
    float* aggr = (float*)ws;          ws += (size_t)N_AGENTS * 128 * 4;
    size_t zero_bytes = (size_t)(ws - (char*)d_ws);
    int* rankb  = (int*)ws;            ws += (size_t)N_EDGES * 4;
    int* off    = (int*)ws;            ws += (size_t)(N_AGENTS + 8) * 4;
    f16* nf16   = (f16*)ws;            ws += (size_t)N_NODES * ND * 2;
    f16* F1     = (f16*)ws;            ws += (size_t)160 * 256 * 2;
    f16* F2     = (f16*)ws;            ws += (size_t)256 * 128 * 2;
    f16* F3     = (f16*)ws;            ws += (size_t)128 * 256 * 2;
    f16* F4     = (f16*)ws;            ws += (size_t)256 * 256 * 2;

    hipMemsetAsync(d_ws, 0, zero_bytes, stream);

    compact_pack_kernel<<<N_EDGES / 256 + 84, 256, 0, stream>>>(
        recv, nf, nf16, rankb, deg, W1, W2, Wh1, Wh2, F1, F2, F3, F4);
    prefix_kernel<<<1, 1024, 0, stream>>>(deg, off);
    scatter_kernel<<<N_EDGES / 256, 256, 0, stream>>>(
        recv, send, rankb, off, eidb, sendb, recvb);
    edge_mlp_mfma<<<(N_AGENTS + RPB - 1) / RPB, 512, 0, stream>>>(
        nf16, ef, F1, F2, b1, b2, wg, bg, sendb, recvb, eidb, off, aggr, den);
    agg_agent_mfma<<<(N_AGENTS + 31) / 32, 1024, 0, stream>>>(
        aggr, den, F3, F4, bh1, bh2, Wout, bout, (float*)d_out);
}

// Round 9
// 467.997 us; speedup vs baseline: 1.1166x; 1.1094x over previous
//
#include <hip/hip_runtime.h>
#include <hip/hip_bf16.h>

#define N_NODES  50000
#define N_EDGES  800000
#define ND       64
#define ED       32
#define MSGD     128
#define HIDD     256
#define N_AGENTS 25000
#define EPAD     800064   // N_EDGES + 64 (tile padding)
#define RPB      49       // receivers per edge-MLP block (511 blocks)

typedef _Float16 f16;
typedef __attribute__((ext_vector_type(4))) _Float16 f16x4;
typedef __attribute__((ext_vector_type(8))) _Float16 f16x8;
typedef __attribute__((ext_vector_type(4))) float f32x4;
typedef unsigned short u16;
typedef unsigned int   u32;
typedef unsigned long long u64;

// ============================================================================
// compact + nf->f16 + weight pack fused.
// Blocks [0, 3125): compact path. Blocks [3125, 3209): pack path.
// ============================================================================
__global__ __launch_bounds__(256) void compact_pack_kernel(
    const int* __restrict__ recv, const float* __restrict__ nf,
    f16* __restrict__ nf16, int* __restrict__ rankb, int* __restrict__ deg,
    const float* __restrict__ W1, const float* __restrict__ W2,
    const float* __restrict__ Wh1, const float* __restrict__ Wh2,
    f16* __restrict__ F1, f16* __restrict__ F2,
    f16* __restrict__ F3, f16* __restrict__ F4)
{
    int b = blockIdx.x;
    if (b >= N_EDGES / 256) {
        // frag for 16x16x32: lane l, elem j <-> W[k=ks*32+(l>>4)*8+j][n=nt*16+(l&15)]
        int tid  = (b - N_EDGES / 256) * 256 + threadIdx.x;
        int grp  = tid >> 6, lane = tid & 63;
        const float* W; f16* D; int NT, stride, gl;
        if      (grp < 80)  { W = W1;  D = F1; NT = 16; stride = 256; gl = grp; }
        else if (grp < 144) { W = W2;  D = F2; NT = 8;  stride = 128; gl = grp - 80; }
        else if (grp < 208) { W = Wh1; D = F3; NT = 16; stride = 256; gl = grp - 144; }
        else if (grp < 336) { W = Wh2; D = F4; NT = 16; stride = 256; gl = grp - 208; }
        else return;
        int ks = gl / NT, nt = gl - ks * NT;
        int n  = nt * 16 + (lane & 15);
        int k0 = ks * 32 + (lane >> 4) * 8;
        f16* dst = D + ((size_t)gl * 64 + lane) * 8;
        #pragma unroll
        for (int j = 0; j < 8; ++j)
            dst[j] = (f16)W[(size_t)(k0 + j) * stride + n];
        return;
    }
    int i = b * 256 + threadIdx.x;
    {   // nf -> f16 (coalesced float4 read, f16x4 write)
        float4 v = ((const float4*)nf)[i];
        f16x4 h;
        h.x = (f16)v.x; h.y = (f16)v.y; h.z = (f16)v.z; h.w = (f16)v.w;
        ((f16x4*)nf16)[i] = h;
    }
    int r = recv[i];
    if (r < N_AGENTS)
        rankb[i] = atomicAdd(&deg[r], 1);   // 25k addresses, pipelined (R14)
}

// ============================================================================
// prefix: exclusive scan deg -> off[25001] (single block)
// ============================================================================
__global__ __launch_bounds__(1024) void prefix_kernel(
    const int* __restrict__ deg, int* __restrict__ off)
{
    __shared__ int part[1024];
    int t = threadIdx.x;
    int i0 = t * 25;
    int s = 0;
    #pragma unroll 1
    for (int i = 0; i < 25; ++i) {
        int idx = i0 + i;
        if (idx < N_AGENTS) s += deg[idx];
    }
    part[t] = s;
    __syncthreads();
    for (int d = 1; d < 1024; d <<= 1) {
        int v = (t >= d) ? part[t - d] : 0;
        __syncthreads();
        part[t] += v;
        __syncthreads();
    }
    int run = (t == 0) ? 0 : part[t - 1];
    #pragma unroll 1
    for (int i = 0; i < 25; ++i) {
        int idx = i0 + i;
        if (idx < N_AGENTS) {
            off[idx] = run;
            run += deg[idx];
        }
    }
    if (t == 1023) off[N_AGENTS] = part[1023];
}

// ============================================================================
// scatter (no atomics): iterate ALL edges; pos = off[recv] + rankb.
// ============================================================================
__global__ __launch_bounds__(256) void scatter_kernel(
    const int* __restrict__ recv, const int* __restrict__ send,
    const int* __restrict__ rankb, const int* __restrict__ off,
    int* __restrict__ eidb, int* __restrict__ sendb, int* __restrict__ recvb)
{
    int i = blockIdx.x * 256 + threadIdx.x;
    int r = recv[i];
    if (r < N_AGENTS) {
        int pos = off[r] + rankb[i];
        eidb[pos]  = i;
        sendb[pos] = send[i];
        recvb[pos] = r;
    }
}

// ============================================================================
// Edge MLP + owned aggregation, LDS-accumulator form (R19).
// R18 post-mortem: traffic fix verified (WRITE 106->18 MB) but the 32-iter
// SERIAL segmented scan on 129 threads added ~3100 cyc/tile (147->274 us).
// R19: persistent LDS accumulator agg_lds[RPB][128] (+25 KB, still 2
// blocks/CU). Per tile, ALL 512 threads: register run-sum over their own
// (col, 8-row group) then 1-2 LDS atomicAdd (ds_add_f32; bank=col&31 ->
// 2-way, free). Global aggr/den written ONCE per block at the end with plain
// coalesced stores (also covers deg-0 receivers -> aggr/den memset dropped).
// Staging + MFMA phases byte-identical to R14 (147 us, FETCH 71->52 MB).
// HARD RULE (R8/R9/R15): staging = combined load+ds_write ROLLED loop +
// __syncthreads. Barrier structure unchanged (B1/B2/B2b).
// ============================================================================
__global__ __launch_bounds__(512, 4) void edge_mlp_mfma(
    const f16* __restrict__ nf16, const float* __restrict__ ef,
    const f16* __restrict__ F1, const f16* __restrict__ F2,
    const float* __restrict__ b1, const float* __restrict__ b2,
    const float* __restrict__ wg, const float* __restrict__ bg,
    const int* __restrict__ sendb, const int* __restrict__ recvb,
    const int* __restrict__ eidb, const int* __restrict__ off,
    float* __restrict__ aggr, float* __restrict__ den)
{
    __shared__ __align__(16) f16 XF[2][10][64][8];  // 20 KB (double buffer)
    __shared__ __align__(16) f16 HB[16][64][8];     // 16 KB
    __shared__ __align__(16) f16 msgt[32][136];     // 8.5 KB
    __shared__ float lpart[8][32];
    __shared__ float evt[32];
    __shared__ int   recvt[32];
    __shared__ float agg_lds[RPB][128];             // 24.5 KB
    __shared__ float den_lds[RPB];

    const int tid  = threadIdx.x;
    const int wv   = tid >> 6;
    const int lane = tid & 63;
    const int q    = lane >> 4;
    const int li   = lane & 15;

    // ---- owned receiver range -> contiguous CSR edge range ----
    const int rb0 = blockIdx.x * RPB;
    if (rb0 >= N_AGENTS) return;
    const int rb1 = min(rb0 + RPB, N_AGENTS);
    const int eb0 = off[rb0];
    const int eb1 = off[rb1];
    const int ntiles = (eb1 - eb0 + 31) >> 5;

    // zero the block accumulator
    for (int idx = tid; idx < RPB * 128; idx += 512)
        agg_lds[idx >> 7][idx & 127] = 0.f;
    if (tid < RPB) den_lds[tid] = 0.f;

    // stationary weight fragments: W1 2 col-tiles + W2 1 col-tile per wave
    f16x8 w1[2][5], w2[8];
    #pragma unroll
    for (int ntl = 0; ntl < 2; ++ntl)
        #pragma unroll
        for (int ks = 0; ks < 5; ++ks)
            w1[ntl][ks] = *(const f16x8*)(F1 + (((size_t)(ks * 16 + 2 * wv + ntl)) * 64 + lane) * 8);
    #pragma unroll
    for (int ks = 0; ks < 8; ++ks)
        w2[ks] = *(const f16x8*)(F2 + (((size_t)(ks * 8 + wv)) * 64 + lane) * 8);

    const float4 ba  = *(const float4*)&b1[wv * 32 + q * 4];
    const float4 bb  = *(const float4*)&b1[wv * 32 + 16 + q * 4];
    const float4 bc  = *(const float4*)&b2[wv * 16 + q * 4];
    const float4 wg4 = *(const float4*)&wg[wv * 16 + q * 4];
    const float  bgv = bg[0];

    // ---- prologue: stage first tile into XF[0] (R10 idiom — rolled) ----
    if (ntiles > 0) {
        const int e0p = eb0;
        f16 (*XFd)[64][8] = XF[0];
        for (int idx = tid; idx < 768; idx += 512) {
            int e = idx / 24, g = idx - e * 24;
            int cp = e0p + e;
            if (g < 16) {
                int node = (g < 8) ? sendb[cp] : recvb[cp];
                f16x8 h = *(const f16x8*)(nf16 + (size_t)node * 64 + (g & 7) * 8);
                int slt = (e >> 4) * 5 + (g >> 2);
                int ln  = (e & 15) + 16 * (g & 3);
                *(f16x8*)&XFd[slt][ln][0] = h;
            } else {
                int eid = eidb[cp];
                float4 v = ((const float4*)ef)[(size_t)eid * 8 + (g - 16)];
                int k0  = 128 + (g - 16) * 4;
                int slt = (e >> 4) * 5 + 4;
                int ln  = (e & 15) + 16 * ((k0 & 31) >> 3);
                int j0  = k0 & 7;
                f16x4 h;
                h.x = (f16)v.x; h.y = (f16)v.y; h.z = (f16)v.z; h.w = (f16)v.w;
                *(f16x4*)&XFd[slt][ln][j0] = h;
            }
        }
    }
    __syncthreads();

    int p = 0;
    for (int t = 0; t < ntiles; ++t) {
        const int e0 = eb0 + t * 32;

        // ---- stage NEXT tile into XF[p^1] — no barrier before layer1 ----
        if (t + 1 < ntiles) {
            const int e0n = e0 + 32;
            f16 (*XFd)[64][8] = XF[p ^ 1];
            for (int idx = tid; idx < 768; idx += 512) {
                int e = idx / 24, g = idx - e * 24;
                int cp = e0n + e;
                if (g < 16) {
                    int node = (g < 8) ? sendb[cp] : recvb[cp];
                    f16x8 h = *(const f16x8*)(nf16 + (size_t)node * 64 + (g & 7) * 8);
                    int slt = (e >> 4) * 5 + (g >> 2);
                    int ln  = (e & 15) + 16 * (g & 3);
                    *(f16x8*)&XFd[slt][ln][0] = h;
                } else {
                    int eid = eidb[cp];
                    float4 v = ((const float4*)ef)[(size_t)eid * 8 + (g - 16)];
                    int k0  = 128 + (g - 16) * 4;
                    int slt = (e >> 4) * 5 + 4;
                    int ln  = (e & 15) + 16 * ((k0 & 31) >> 3);
                    int j0  = k0 & 7;
                    f16x4 h;
                    h.x = (f16)v.x; h.y = (f16)v.y; h.z = (f16)v.z; h.w = (f16)v.w;
                    *(f16x4*)&XFd[slt][ln][j0] = h;
                }
            }
        }

        // ---- layer 1: h[col][edge] = W1^T x^T (from XF[p]) ----
        f32x4 acc[2][2];   // [eh][ntl]
        acc[0][0] = f32x4{ba.x, ba.y, ba.z, ba.w}; acc[1][0] = acc[0][0];
        acc[0][1] = f32x4{bb.x, bb.y, bb.z, bb.w}; acc[1][1] = acc[0][1];
        #pragma unroll
        for (int ks = 0; ks < 5; ++ks)
            #pragma unroll
            for (int eh = 0; eh < 2; ++eh) {
                f16x8 xh = *(const f16x8*)XF[p][eh * 5 + ks][lane];
                acc[eh][0] = __builtin_amdgcn_mfma_f32_16x16x32_f16(w1[0][ks], xh, acc[eh][0], 0, 0, 0);
                acc[eh][1] = __builtin_amdgcn_mfma_f32_16x16x32_f16(w1[1][ks], xh, acc[eh][1], 0, 0, 0);
            }
        // relu + stash h as layer-2 B frags
        #pragma unroll
        for (int eh = 0; eh < 2; ++eh)
            #pragma unroll
            for (int ntl = 0; ntl < 2; ++ntl) {
                f16x4 hv;
                hv.x = (f16)fmaxf(acc[eh][ntl][0], 0.f);
                hv.y = (f16)fmaxf(acc[eh][ntl][1], 0.f);
                hv.z = (f16)fmaxf(acc[eh][ntl][2], 0.f);
                hv.w = (f16)fmaxf(acc[eh][ntl][3], 0.f);
                int l2 = li + 16 * (2 * ntl + (q >> 1));
                int j0 = (q & 1) * 4;
                *(f16x4*)&HB[eh * 8 + wv][l2][j0] = hv;
            }
        __syncthreads();   // B1: HB ready; XF[p^1] staged

        // ---- layer 2: msg[col][edge] = W2^T h^T ----
        f32x4 acc2[2];
        acc2[0] = f32x4{bc.x, bc.y, bc.z, bc.w}; acc2[1] = acc2[0];
        #pragma unroll
        for (int ks2 = 0; ks2 < 8; ++ks2)
            #pragma unroll
            for (int eh = 0; eh < 2; ++eh) {
                f16x8 hh = *(const f16x8*)HB[eh * 8 + ks2][lane];
                acc2[eh] = __builtin_amdgcn_mfma_f32_16x16x32_f16(w2[ks2], hh, acc2[eh], 0, 0, 0);
            }
        // relu + gate partial + msg stash
        {
            float pr[2];
            #pragma unroll
            for (int eh = 0; eh < 2; ++eh) {
                float v0 = fmaxf(acc2[eh][0], 0.f);
                float v1 = fmaxf(acc2[eh][1], 0.f);
                float v2 = fmaxf(acc2[eh][2], 0.f);
                float v3 = fmaxf(acc2[eh][3], 0.f);
                f16x4 mm;
                mm.x = (f16)v0; mm.y = (f16)v1; mm.z = (f16)v2; mm.w = (f16)v3;
                *(f16x4*)&msgt[eh * 16 + li][wv * 16 + q * 4] = mm;
                float pp = v0 * wg4.x + v1 * wg4.y + v2 * wg4.z + v3 * wg4.w;
                pp += __shfl_xor(pp, 16, 64);
                pp += __shfl_xor(pp, 32, 64);
                pr[eh] = pp;
            }
            if (lane < 16) {
                lpart[wv][li]      = pr[0];
                lpart[wv][16 + li] = pr[1];
            }
        }
        __syncthreads();   // B2: msgt/lpart ready

        // ---- gate: e = exp(logit); publish evt/recvt for this tile ----
        if (tid < 32) {
            int pos = e0 + tid;
            int r = -1; float e = 0.f;
            if (pos < eb1) {
                r = recvb[pos];
                float s2 = bgv;
                #pragma unroll
                for (int w = 0; w < 8; ++w) s2 += lpart[w][tid];
                e = expf(s2);   // softmax shift-invariant; |logit|~O(5)
            }
            evt[tid]   = e;
            recvt[tid] = r;
        }
        __syncthreads();   // B2b: evt/recvt ready

        // ---- parallel owned accumulate: 512 threads, (col, 8-row group),
        //      register run-sum + 1-2 LDS atomics (ds_add_f32) ----
        {
            const int rg  = tid >> 7;      // 0..3
            const int col = tid & 127;
            float run = 0.f; int rl_open = -1;
            #pragma unroll
            for (int j = 0; j < 8; ++j) {
                int row = rg * 8 + j;
                int r  = recvt[row];
                int rl = (r >= 0) ? (r - rb0) : -1;
                if (rl != rl_open) {
                    if (rl_open >= 0) atomicAdd(&agg_lds[rl_open][col], run);
                    run = 0.f; rl_open = rl;
                }
                if (rl >= 0) run = fmaf(evt[row], (float)msgt[row][col], run);
            }
            if (rl_open >= 0) atomicAdd(&agg_lds[rl_open][col], run);
            if (col == 0) {   // den by the 4 col-0 threads
                float drun = 0.f; int dopen = -1;
                #pragma unroll
                for (int j = 0; j < 8; ++j) {
                    int row = rg * 8 + j;
                    int r  = recvt[row];
                    int rl = (r >= 0) ? (r - rb0) : -1;
                    if (rl != dopen) {
                        if (dopen >= 0) atomicAdd(&den_lds[dopen], drun);
                        drun = 0.f; dopen = rl;
                    }
                    if (rl >= 0) drun += evt[row];
                }
                if (dopen >= 0) atomicAdd(&den_lds[dopen], drun);
            }
        }
        p ^= 1;
    }

    // ---- single coalesced flush (also zeroes deg-0 receivers' slots) ----
    __syncthreads();
    for (int idx = tid; idx < RPB * 128; idx += 512) {
        int rl = idx >> 7, c = idx & 127;
        int r = rb0 + rl;
        if (r < rb1) aggr[(size_t)r * 128 + c] = agg_lds[rl][c];
    }
    if (tid < RPB && rb0 + tid < rb1) den[rb0 + tid] = den_lds[tid];
}

// ============================================================================
// Agent MLP. Aggregation already done (aggr/den owned-stores from edge_mlp):
// normalize into XA fragments and run the 2-layer fp16-MFMA MLP.
// ============================================================================
__global__ __launch_bounds__(1024, 4) void agg_agent_mfma(
    const float* __restrict__ aggr, const float* __restrict__ den,
    const f16* __restrict__ F3, const f16* __restrict__ F4,
    const float* __restrict__ bh1, const float* __restrict__ bh2,
    const float* __restrict__ Wout, const float* __restrict__ bout,
    float* __restrict__ out)
{
    __shared__ __align__(16) f16 XA[8][64][8];     // 8 KB
    __shared__ __align__(16) f16 HB2[16][64][8];   // 16 KB
    __shared__ float lpart[16][32];

    const int tid  = threadIdx.x;
    const int wv   = tid >> 6;
    const int lane = tid & 63;
    const int q    = lane >> 4;
    const int li   = lane & 15;
    const int a0i  = blockIdx.x * 32;

    // ---- normalize aggr into XA fragment layout ----
    {
        int g = tid >> 5, c = tid & 31;   // receiver a0i+g, cols [c*4, c*4+4)
        int r = a0i + g;
        float4 a = make_float4(0.f, 0.f, 0.f, 0.f);
        float d = 1e-9f;
        if (r < N_AGENTS) {
            a = *(const float4*)&aggr[(size_t)r * 128 + c * 4];
            d += den[r];
        }
        float inv = 1.0f / d;
        int k0   = c * 4;
        int slot = (g >> 4) * 4 + (k0 >> 5);
        int ln   = (g & 15) + 16 * ((k0 & 31) >> 3);
        int j0   = k0 & 7;
        f16x4 h;
        h.x = (f16)(a.x * inv); h.y = (f16)(a.y * inv);
        h.z = (f16)(a.z * inv); h.w = (f16)(a.w * inv);
        *(f16x4*)&XA[slot][ln][j0] = h;
    }
    __syncthreads();

    // ---- weight fragments + layer 1 ----
    f16x8 wh1[4], wh2[8];
    #pragma unroll
    for (int ks = 0; ks < 4; ++ks)
        wh1[ks] = *(const f16x8*)(F3 + (((size_t)(ks * 16 + wv)) * 64 + lane) * 8);
    #pragma unroll
    for (int ks = 0; ks < 8; ++ks)
        wh2[ks] = *(const f16x8*)(F4 + (((size_t)(ks * 16 + wv)) * 64 + lane) * 8);

    f32x4 acc[2] = {};
    #pragma unroll
    for (int ks = 0; ks < 4; ++ks)
        #pragma unroll
        for (int eh = 0; eh < 2; ++eh) {
            f16x8 xh = *(const f16x8*)XA[eh * 4 + ks][lane];
            acc[eh] = __builtin_amdgcn_mfma_f32_16x16x32_f16(wh1[ks], xh, acc[eh], 0, 0, 0);
        }
    {
        const float4 b1v = ((const float4*)bh1)[wv * 4 + q];
        #pragma unroll
        for (int eh = 0; eh < 2; ++eh) {
            f16x4 hv;
            hv.x = (f16)fmaxf(acc[eh][0] + b1v.x, 0.f);
            hv.y = (f16)fmaxf(acc[eh][1] + b1v.y, 0.f);
            hv.z = (f16)fmaxf(acc[eh][2] + b1v.z, 0.f);
            hv.w = (f16)fmaxf(acc[eh][3] + b1v.w, 0.f);
            int l2 = li + 16 * ((wv & 1) * 2 + (q >> 1));
            int j0 = (q & 1) * 4;
            *(f16x4*)&HB2[eh * 8 + (wv >> 1)][l2][j0] = hv;
        }
    }
    __syncthreads();

    // ---- layer 2 + output partial ----
    f32x4 acc2[2] = {};
    #pragma unroll
    for (int ks2 = 0; ks2 < 8; ++ks2)
        #pragma unroll
        for (int eh = 0; eh < 2; ++eh) {
            f16x8 hh = *(const f16x8*)HB2[eh * 8 + ks2][lane];
            acc2[eh] = __builtin_amdgcn_mfma_f32_16x16x32_f16(wh2[ks2], hh, acc2[eh], 0, 0, 0);
        }
    {
        const float4 b2v = ((const float4*)bh2)[wv * 4 + q];
        const float4 wo4 = ((const float4*)Wout)[wv * 4 + q];
        float pr[2];
        #pragma unroll
        for (int eh = 0; eh < 2; ++eh) {
            float pp = fmaxf(acc2[eh][0] + b2v.x, 0.f) * wo4.x
                     + fmaxf(acc2[eh][1] + b2v.y, 0.f) * wo4.y
                     + fmaxf(acc2[eh][2] + b2v.z, 0.f) * wo4.z
                     + fmaxf(acc2[eh][3] + b2v.w, 0.f) * wo4.w;
            pp += __shfl_xor(pp, 16, 64);
            pp += __shfl_xor(pp, 32, 64);
            pr[eh] = pp;
        }
        if (lane < 16) {
            lpart[wv][li]      = pr[0];
            lpart[wv][16 + li] = pr[1];
        }
    }
    __syncthreads();

    if (tid < 32 && a0i + tid < N_AGENTS) {
        float s = bout[0];
        #pragma unroll
        for (int w = 0; w < 16; ++w) s += lpart[w][tid];
        out[a0i + tid] = tanhf(s);
    }
}

// ============================================================================
extern "C" void kernel_launch(void* const* d_in, const int* in_sizes, int n_in,
                              void* d_out, int out_size, void* d_ws, size_t ws_size,
                              hipStream_t stream)
{
    const float* nf   = (const float*)d_in[0];
    const float* ef   = (const float*)d_in[1];
    const float* W1   = (const float*)d_in[2];
    const float* b1   = (const float*)d_in[3];
    const float* W2   = (const float*)d_in[4];
    const float* b2   = (const float*)d_in[5];
    const float* wg   = (const float*)d_in[6];
    const float* bg   = (const float*)d_in[7];
    const float* Wh1  = (const float*)d_in[8];
    const float* bh1  = (const float*)d_in[9];
    const float* Wh2  = (const float*)d_in[10];
    const float* bh2  = (const float*)d_in[11];
    const float* Wout = (const float*)d_in[12];
    const float* bout = (const float*)d_in[13];
    const int*   send = (const int*)d_in[14];
    const int*   recv = (const int*)d_in[15];

    // workspace: [deg|eidb|sendb|recvb] zeroed (tail slots of the last padded
    // tile must gather row 0). aggr/den NOT zeroed: edge_mlp's flush writes
    // every owned slot (including deg-0 receivers).
    char* ws = (char*)d_ws;
    int* deg    = (int*)ws;            ws += (size_t)N_AGENTS * 4;
    int* eidb   = (int*)ws;            ws += (size_t)EPAD * 4;
    int* sendb  = (int*)ws;            ws += (size_t)EPAD * 4;
    int* recvb  = (int*)ws;            ws += (size_t)EPAD * 4;
    size_t zero_bytes = (size_t)(ws - (char*)d_ws);
    float* den  = (float*)ws;          ws += (size_t)N_AGENTS * 4;
    float* aggr = (float*)ws;          ws += (size_t)N_AGENTS * 128 * 4;
    int* rankb  = (int*)ws;            ws += (size_t)N_EDGES * 4;
    int* off    = (int*)ws;            ws += (size_t)(N_AGENTS + 8) * 4;
    f16* nf16   = (f16*)ws;            ws += (size_t)N_NODES * ND * 2;
    f16* F1     = (f16*)ws;            ws += (size_t)160 * 256 * 2;
    f16* F2     = (f16*)ws;            ws += (size_t)256 * 128 * 2;
    f16* F3     = (f16*)ws;            ws += (size_t)128 * 256 * 2;
    f16* F4     = (f16*)ws;            ws += (size_t)256 * 256 * 2;

    hipMemsetAsync(d_ws, 0, zero_bytes, stream);

    compact_pack_kernel<<<N_EDGES / 256 + 84, 256, 0, stream>>>(
        recv, nf, nf16, rankb, deg, W1, W2, Wh1, Wh2, F1, F2, F3, F4);
    prefix_kernel<<<1, 1024, 0, stream>>>(deg, off);
    scatter_kernel<<<N_EDGES / 256, 256, 0, stream>>>(
        recv, send, rankb, off, eidb, sendb, recvb);
    edge_mlp_mfma<<<(N_AGENTS + RPB - 1) / RPB, 512, 0, stream>>>(
        nf16, ef, F1, F2, b1, b2, wg, bg, sendb, recvb, eidb, off, aggr, den);
    agg_agent_mfma<<<(N_AGENTS + 31) / 32, 1024, 0, stream>>>(
        aggr, den, F3, F4, bh1, bh2, Wout, bout, (float*)d_out);
}